// Round 1
// baseline (2133.376 us; speedup 1.0000x reference)
//
#include <hip/hip_runtime.h>

// EnhancedRWKVBlock on MI355X.
// Structure: everything reduces to 7 bf16 MFMA GEMMs + cheap elementwise/LN glue.
//   ln1(x) -> h ; lw = softmax(h@lvl_w+lvl_b)
//   v = h@Wv ; k = h@Wk ; r = sigmoid(h@Wr)
//   u = r * sum_d lw_d * (att_state*decay + k*v)      (no recurrence in reference!)
//   x1 = x + u@Wo                                     (x1 kept fp32 in d_out)
//   h2 = ln2(x1) ; km = h2*tmk + shift(h2)*(1-tmk)
//   kk = relu(km@Wkey)^2
//   out = x1 + (kk@Wval) * sigmoid(kk@Wgate)
// GEMM: m97-style 128x128 tile, 16x16x32 bf16 MFMA, global_load_lds width=16.

typedef unsigned short u16;
typedef short short8 __attribute__((ext_vector_type(8)));
typedef float f32x4 __attribute__((ext_vector_type(4)));
typedef unsigned short u16x4 __attribute__((ext_vector_type(4)));

#define GAS(p) (const __attribute__((address_space(1))) void*)(p)
#define LAS(p) (__attribute__((address_space(3))) void*)(p)

__device__ __forceinline__ float bf2f(u16 h) { return __uint_as_float(((unsigned)h) << 16); }
__device__ __forceinline__ u16 f2bf(float f) {
  unsigned u = __float_as_uint(f);
  u += 0x7FFFu + ((u >> 16) & 1u);   // round-to-nearest-even
  return (u16)(u >> 16);
}
__device__ __forceinline__ float sigmoidf_(float x) { return 1.f / (1.f + expf(-x)); }

// ---------------------------------------------------------------- transpose+convert
// in: fp32 [R,C] row-major -> out: bf16 [C,R] row-major. R,C multiples of 32.
__global__ __launch_bounds__(256) void transpose_bf16_kernel(
    const float* __restrict__ in, u16* __restrict__ out, int R, int C) {
  __shared__ float tile[32][33];
  const int cb = blockIdx.x * 32, rb = blockIdx.y * 32;
  const int tx = threadIdx.x, ty = threadIdx.y;  // (32,8)
#pragma unroll
  for (int i = 0; i < 32; i += 8)
    tile[ty + i][tx] = in[(size_t)(rb + ty + i) * C + (cb + tx)];
  __syncthreads();
#pragma unroll
  for (int i = 0; i < 32; i += 8)
    out[(size_t)(cb + ty + i) * R + (rb + tx)] = f2bf(tile[tx][ty + i]);
}

// ---------------------------------------------------------------- LayerNorm (+optional lw softmax)
// one block per row (H=2048, 256 threads, 8 elems/thread)
template <bool WITH_LW>
__global__ __launch_bounds__(256) void ln_kernel(
    const float* __restrict__ x, const float* __restrict__ sc, const float* __restrict__ bi,
    u16* __restrict__ hout,
    const float* __restrict__ lvlw, const float* __restrict__ lvlb,
    float* __restrict__ lwout) {
  const int tid = threadIdx.x;
  const int row = blockIdx.x;
  const int wv = tid >> 6, ln = tid & 63;
  const float* xr = x + (size_t)row * 2048;
  f32x4 a0 = *(const f32x4*)(xr + tid * 4);
  f32x4 a1 = *(const f32x4*)(xr + 1024 + tid * 4);
  float s = a0[0] + a0[1] + a0[2] + a0[3] + a1[0] + a1[1] + a1[2] + a1[3];
  float q = a0[0]*a0[0] + a0[1]*a0[1] + a0[2]*a0[2] + a0[3]*a0[3]
          + a1[0]*a1[0] + a1[1]*a1[1] + a1[2]*a1[2] + a1[3]*a1[3];
#pragma unroll
  for (int off = 32; off; off >>= 1) { s += __shfl_down(s, off); q += __shfl_down(q, off); }
  __shared__ float red[8];
  __shared__ float stats[2];
  if (ln == 0) { red[wv] = s; red[4 + wv] = q; }
  __syncthreads();
  if (tid == 0) {
    float S1 = red[0] + red[1] + red[2] + red[3];
    float S2 = red[4] + red[5] + red[6] + red[7];
    float m = S1 * (1.f / 2048.f);
    float var = S2 * (1.f / 2048.f) - m * m;
    stats[0] = m;
    stats[1] = rsqrtf(var + 1e-5f);
  }
  __syncthreads();
  const float m = stats[0], rs = stats[1];
  f32x4 s0 = *(const f32x4*)(sc + tid * 4), s1 = *(const f32x4*)(sc + 1024 + tid * 4);
  f32x4 b0 = *(const f32x4*)(bi + tid * 4), b1 = *(const f32x4*)(bi + 1024 + tid * 4);
  float h0[4], h1[4];
  u16x4 o0, o1;
#pragma unroll
  for (int e = 0; e < 4; e++) {
    h0[e] = (a0[e] - m) * rs * s0[e] + b0[e];
    h1[e] = (a1[e] - m) * rs * s1[e] + b1[e];
    o0[e] = f2bf(h0[e]);
    o1[e] = f2bf(h1[e]);
  }
  u16* hr = hout + (size_t)row * 2048;
  *(u16x4*)(hr + tid * 4) = o0;
  *(u16x4*)(hr + 1024 + tid * 4) = o1;

  if constexpr (WITH_LW) {
    f32x4 acc = (f32x4){0.f, 0.f, 0.f, 0.f};
#pragma unroll
    for (int e = 0; e < 4; e++)
      acc += (*(const f32x4*)(lvlw + (size_t)(tid * 4 + e) * 4)) * h0[e];
#pragma unroll
    for (int e = 0; e < 4; e++)
      acc += (*(const f32x4*)(lvlw + (size_t)(1024 + tid * 4 + e) * 4)) * h1[e];
#pragma unroll
    for (int off = 32; off; off >>= 1) {
      acc[0] += __shfl_down(acc[0], off);
      acc[1] += __shfl_down(acc[1], off);
      acc[2] += __shfl_down(acc[2], off);
      acc[3] += __shfl_down(acc[3], off);
    }
    __shared__ float red4[16];
    if (ln == 0) {
      red4[wv * 4 + 0] = acc[0]; red4[wv * 4 + 1] = acc[1];
      red4[wv * 4 + 2] = acc[2]; red4[wv * 4 + 3] = acc[3];
    }
    __syncthreads();
    if (tid == 0) {
      float lg[4];
#pragma unroll
      for (int d = 0; d < 4; d++)
        lg[d] = red4[d] + red4[4 + d] + red4[8 + d] + red4[12 + d] + lvlb[d];
      float mx = fmaxf(fmaxf(lg[0], lg[1]), fmaxf(lg[2], lg[3]));
      float e0 = expf(lg[0] - mx), e1 = expf(lg[1] - mx), e2 = expf(lg[2] - mx), e3 = expf(lg[3] - mx);
      float inv = 1.f / (e0 + e1 + e2 + e3);
      float* lr = lwout + (size_t)row * 4;
      lr[0] = e0 * inv; lr[1] = e1 * inv; lr[2] = e2 * inv; lr[3] = e3 * inv;
    }
  }
}

// ---------------------------------------------------------------- attention mix: u = r*(sum_d lw_d*(as*decay + k*v))
__global__ __launch_bounds__(256) void mix_u_kernel(
    const u16* __restrict__ v, const u16* __restrict__ k, const u16* __restrict__ r,
    const float* __restrict__ lw, const float* __restrict__ att, const float* __restrict__ td,
    u16* __restrict__ u) {
  const size_t i4 = ((size_t)blockIdx.x * 256 + threadIdx.x) * 4;
  const int row = (int)(i4 >> 11);
  const int hh = (int)(i4 & 2047);
  const int b = row >> 11;
  f32x4 lwv = *(const f32x4*)(lw + (size_t)row * 4);
  u16x4 k_ = *(const u16x4*)(k + i4);
  u16x4 v_ = *(const u16x4*)(v + i4);
  u16x4 r_ = *(const u16x4*)(r + i4);
  f32x4 kv, acc = (f32x4){0.f, 0.f, 0.f, 0.f};
#pragma unroll
  for (int e = 0; e < 4; e++) kv[e] = bf2f(k_[e]) * bf2f(v_[e]);
#pragma unroll
  for (int d = 0; d < 4; d++) {
    f32x4 as_ = *(const f32x4*)(att + (size_t)(b * 4 + d) * 2048 + hh);
    f32x4 tdv = *(const f32x4*)(td + (size_t)d * 2048 + hh);
#pragma unroll
    for (int e = 0; e < 4; e++)
      acc[e] += lwv[d] * (as_[e] * expf(-expf(tdv[e])) + kv[e]);
  }
  u16x4 o;
#pragma unroll
  for (int e = 0; e < 4; e++) o[e] = f2bf(bf2f(r_[e]) * acc[e]);
  *(u16x4*)(u + i4) = o;
}

// ---------------------------------------------------------------- token shift mix: km = h2*tmk + prev*(1-tmk)
__global__ __launch_bounds__(256) void shift_mix_kernel(
    const u16* __restrict__ h2, const float* __restrict__ cm, const float* __restrict__ tmk,
    u16* __restrict__ km) {
  const size_t i4 = ((size_t)blockIdx.x * 256 + threadIdx.x) * 4;
  const int row = (int)(i4 >> 11);
  const int hh = (int)(i4 & 2047);
  const int b = row >> 11;
  const int t = row & 2047;
  f32x4 tk = *(const f32x4*)(tmk + hh);
  u16x4 cur_ = *(const u16x4*)(h2 + i4);
  f32x4 prev;
  if (t == 0) {
    prev = *(const f32x4*)(cm + (size_t)b * 2048 + hh);
  } else {
    u16x4 p_ = *(const u16x4*)(h2 + i4 - 2048);
#pragma unroll
    for (int e = 0; e < 4; e++) prev[e] = bf2f(p_[e]);
  }
  u16x4 o;
#pragma unroll
  for (int e = 0; e < 4; e++) {
    float c = bf2f(cur_[e]);
    o[e] = f2bf(c * tk[e] + prev[e] * (1.f - tk[e]));
  }
  *(u16x4*)(km + i4) = o;
}

// ---------------------------------------------------------------- GEMM: C[M,N] = A[M,K] @ Bt[N,K]^T (bf16 in, fp32 acc)
enum { EPI_BF16 = 0, EPI_SIG, EPI_ADDX, EPI_RELU2, EPI_FINAL };

template <int EPI>
__global__ __launch_bounds__(256) void gemm_bt(
    const u16* __restrict__ A, const u16* __restrict__ Bt,
    void* out, const float* aux_f, const u16* aux_h,
    int M, int N, int K) {
  __shared__ __align__(16) u16 ldsA[128 * 32];
  __shared__ __align__(16) u16 ldsB[128 * 32];
  const int tid = threadIdx.x;
  const int wave = tid >> 6, lane = tid & 63;
  const int qd = lane >> 4, l16 = lane & 15;
  const int m0 = blockIdx.y * 128, n0 = blockIdx.x * 128;
  const int wm = (wave >> 1) * 64, wn = (wave & 1) * 64;

  const u16* Ag = A + (size_t)(m0 + (tid >> 2)) * K + ((tid & 3) << 3);
  const u16* Bg = Bt + (size_t)(n0 + (tid >> 2)) * K + ((tid & 3) << 3);
  const size_t half = (size_t)64 * K;
  u16* la = ldsA + wave * 512;  // wave-uniform base; HW scatters lane*16B
  u16* lb = ldsB + wave * 512;

  f32x4 acc[4][4];
#pragma unroll
  for (int i = 0; i < 4; i++)
#pragma unroll
    for (int j = 0; j < 4; j++) acc[i][j] = (f32x4){0.f, 0.f, 0.f, 0.f};

  for (int kt = 0; kt < K; kt += 32) {
    __builtin_amdgcn_global_load_lds(GAS(Ag + kt), LAS(la), 16, 0, 0);
    __builtin_amdgcn_global_load_lds(GAS(Ag + half + kt), LAS(la + 2048), 16, 0, 0);
    __builtin_amdgcn_global_load_lds(GAS(Bg + kt), LAS(lb), 16, 0, 0);
    __builtin_amdgcn_global_load_lds(GAS(Bg + half + kt), LAS(lb + 2048), 16, 0, 0);
    __syncthreads();
    short8 af[4], bfr[4];
#pragma unroll
    for (int i = 0; i < 4; i++)
      af[i] = *(const short8*)(ldsA + (wm + i * 16 + l16) * 32 + qd * 8);
#pragma unroll
    for (int j = 0; j < 4; j++)
      bfr[j] = *(const short8*)(ldsB + (wn + j * 16 + l16) * 32 + qd * 8);
#pragma unroll
    for (int i = 0; i < 4; i++)
#pragma unroll
      for (int j = 0; j < 4; j++)
        acc[i][j] = __builtin_amdgcn_mfma_f32_16x16x32_bf16(af[i], bfr[j], acc[i][j], 0, 0, 0);
    __syncthreads();
  }

#pragma unroll
  for (int i = 0; i < 4; i++)
#pragma unroll
    for (int j = 0; j < 4; j++)
#pragma unroll
      for (int rg = 0; rg < 4; rg++) {
        const int rr = m0 + wm + i * 16 + qd * 4 + rg;   // C/D: row = quad*4+reg
        const int cc = n0 + wn + j * 16 + l16;           //      col = lane&15
        const size_t idx = (size_t)rr * N + cc;
        const float vv = acc[i][j][rg];
        if constexpr (EPI == EPI_BF16) {
          ((u16*)out)[idx] = f2bf(vv);
        } else if constexpr (EPI == EPI_SIG) {
          ((u16*)out)[idx] = f2bf(sigmoidf_(vv));
        } else if constexpr (EPI == EPI_ADDX) {
          ((float*)out)[idx] = vv + aux_f[idx];
        } else if constexpr (EPI == EPI_RELU2) {
          float t = vv > 0.f ? vv : 0.f;
          ((u16*)out)[idx] = f2bf(t * t);
        } else {  // EPI_FINAL: out = x1 + p*sigmoid(q)
          float x1v = aux_f[idx];
          float pv = bf2f(aux_h[idx]);
          ((float*)out)[idx] = x1v + pv * sigmoidf_(vv);
        }
      }
}

// ---------------------------------------------------------------- launch
extern "C" void kernel_launch(void* const* d_in, const int* in_sizes, int n_in,
                              void* d_out, int out_size, void* d_ws, size_t ws_size,
                              hipStream_t stream) {
  const float* x = (const float*)d_in[0];
  const float* att_state = (const float*)d_in[1];
  const float* cm_state = (const float*)d_in[2];
  const float* ln1_s = (const float*)d_in[3];
  const float* ln1_b = (const float*)d_in[4];
  const float* ln2_s = (const float*)d_in[5];
  const float* ln2_b = (const float*)d_in[6];
  const float* td = (const float*)d_in[7];
  const float* lvl_w = (const float*)d_in[8];
  const float* lvl_b = (const float*)d_in[9];
  const float* Wv = (const float*)d_in[10];
  const float* Wk = (const float*)d_in[11];
  const float* Wr = (const float*)d_in[12];
  const float* Wo = (const float*)d_in[13];
  const float* tmk = (const float*)d_in[14];
  const float* Wkey = (const float*)d_in[15];
  const float* Wval = (const float*)d_in[16];
  const float* Wgate = (const float*)d_in[17];
  float* out = (float*)d_out;

  const size_t S = 8192ull * 2048ull;     // B*T*H
  const size_t S4 = 8192ull * 8192ull;    // B*T*FF
  char* ws = (char*)d_ws;
  u16* bufW = (u16*)(ws);                 // 32 MiB: JIT-transposed weight (reused)
  u16* hbuf = (u16*)(ws + 1 * S * 2);     // h, later u
  u16* vbuf = (u16*)(ws + 2 * S * 2);     // v, later h2
  u16* kbuf = (u16*)(ws + 3 * S * 2);     // k, later km
  u16* rbuf = (u16*)(ws + 4 * S * 2);     // r, later p
  u16* kkbuf = (u16*)(ws + 5 * S * 2);    // 128 MiB: kk
  float* lwbuf = (float*)(ws + 5 * S * 2 + S4 * 2);  // 128 KiB: lw
  (void)in_sizes; (void)n_in; (void)out_size; (void)ws_size;

  const dim3 tb256(256);
  const dim3 ttb(32, 8);
  const dim3 g2k(2048 / 32, 2048 / 32);       // square weight transpose
  const dim3 gkey(8192 / 32, 2048 / 32);      // Wkey [2048,8192] -> [8192,2048]
  const dim3 gvg(2048 / 32, 8192 / 32);       // Wval/Wgate [8192,2048] -> [2048,8192]
  const dim3 gemmN2k(2048 / 128, 8192 / 128); // (16,64)
  const dim3 gemmN8k(8192 / 128, 8192 / 128); // (64,64)
  const int elemBlocks = (int)(S / 1024);     // 4 elems/thread, 256 thr/block

  // ln1 -> h (bf16) + lw softmax
  ln_kernel<true><<<8192, tb256, 0, stream>>>(x, ln1_s, ln1_b, hbuf, lvl_w, lvl_b, lwbuf);
  // v = h@Wv
  transpose_bf16_kernel<<<g2k, ttb, 0, stream>>>(Wv, bufW, 2048, 2048);
  gemm_bt<EPI_BF16><<<gemmN2k, tb256, 0, stream>>>(hbuf, bufW, vbuf, nullptr, nullptr, 8192, 2048, 2048);
  // k = h@Wk
  transpose_bf16_kernel<<<g2k, ttb, 0, stream>>>(Wk, bufW, 2048, 2048);
  gemm_bt<EPI_BF16><<<gemmN2k, tb256, 0, stream>>>(hbuf, bufW, kbuf, nullptr, nullptr, 8192, 2048, 2048);
  // r = sigmoid(h@Wr)
  transpose_bf16_kernel<<<g2k, ttb, 0, stream>>>(Wr, bufW, 2048, 2048);
  gemm_bt<EPI_SIG><<<gemmN2k, tb256, 0, stream>>>(hbuf, bufW, rbuf, nullptr, nullptr, 8192, 2048, 2048);
  // u = r*(sum_d lw_d*(att_state*decay + k*v))  -> hbuf (h dead)
  mix_u_kernel<<<elemBlocks, tb256, 0, stream>>>(vbuf, kbuf, rbuf, lwbuf, att_state, td, hbuf);
  // x1 = x + u@Wo  -> d_out (fp32)
  transpose_bf16_kernel<<<g2k, ttb, 0, stream>>>(Wo, bufW, 2048, 2048);
  gemm_bt<EPI_ADDX><<<gemmN2k, tb256, 0, stream>>>(hbuf, bufW, out, x, nullptr, 8192, 2048, 2048);
  // h2 = ln2(x1) -> vbuf (v dead)
  ln_kernel<false><<<8192, tb256, 0, stream>>>(out, ln2_s, ln2_b, vbuf, nullptr, nullptr, nullptr);
  // km -> kbuf (k dead)
  shift_mix_kernel<<<elemBlocks, tb256, 0, stream>>>(vbuf, cm_state, tmk, kbuf);
  // kk = relu(km@Wkey)^2 -> kkbuf
  transpose_bf16_kernel<<<gkey, ttb, 0, stream>>>(Wkey, bufW, 2048, 8192);
  gemm_bt<EPI_RELU2><<<gemmN8k, tb256, 0, stream>>>(kbuf, bufW, kkbuf, nullptr, nullptr, 8192, 8192, 2048);
  // p = kk@Wval -> rbuf (r dead)
  transpose_bf16_kernel<<<gvg, ttb, 0, stream>>>(Wval, bufW, 8192, 2048);
  gemm_bt<EPI_BF16><<<gemmN2k, tb256, 0, stream>>>(kkbuf, bufW, rbuf, nullptr, nullptr, 8192, 2048, 8192);
  // out = x1 + p*sigmoid(kk@Wgate)  (reads x1 from d_out, writes d_out in place)
  transpose_bf16_kernel<<<gvg, ttb, 0, stream>>>(Wgate, bufW, 8192, 2048);
  gemm_bt<EPI_FINAL><<<gemmN2k, tb256, 0, stream>>>(kkbuf, bufW, out, out, rbuf, 8192, 2048, 8192);
}

// Round 2
// 1977.869 us; speedup vs baseline: 1.0786x; 1.0786x over previous
//
#include <hip/hip_runtime.h>

// EnhancedRWKVBlock on MI355X — round 2.
//   ln1(x) -> h ; lw = softmax(h@lvl_w+lvl_b)
//   [v|k|r] = h @ [Wv|Wk|Wr]  (ONE fused GEMM, N=6144, 3072 blocks)
//   u = r * sum_d lw_d * (att_state*decay + k*v)
//   x1 = x + u@Wo                      (fp32, in d_out)
//   h2 = ln2(x1) ; km = tokenshift mix
//   kk = relu(km@Wkey)^2
//   out = x1 + (kk@Wval) * sigmoid(kk@Wgate)   (ONE fused GEMM, column-interleaved
//                                               Bt, epilogue combines via shfl_xor)
// GEMM core: m97-style 128x128 tile, 16x16x32 bf16 MFMA, global_load_lds w=16.
// Round-2 change rationale: 1024-block grids on ~768 concurrent-block slots ran
// at 67% slot utilization (tail quantization). Fused grids (3072 / 2048) fix it.

typedef unsigned short u16;
typedef short short8 __attribute__((ext_vector_type(8)));
typedef float f32x4 __attribute__((ext_vector_type(4)));
typedef unsigned short u16x4 __attribute__((ext_vector_type(4)));

#define GAS(p) (const __attribute__((address_space(1))) void*)(p)
#define LAS(p) (__attribute__((address_space(3))) void*)(p)

__device__ __forceinline__ float bf2f(u16 h) { return __uint_as_float(((unsigned)h) << 16); }
__device__ __forceinline__ u16 f2bf(float f) {
  unsigned u = __float_as_uint(f);
  u += 0x7FFFu + ((u >> 16) & 1u);   // round-to-nearest-even
  return (u16)(u >> 16);
}
__device__ __forceinline__ float sigmoidf_(float x) { return 1.f / (1.f + expf(-x)); }

// ---------------------------------------------------------------- transpose+convert
// in: fp32 [R,C] row-major -> out bf16: out[(c*rs + ro)*R + r] = in[r*C + c].
// rs/ro let several weights land interleaved or at row offsets in one Bt buffer.
__global__ __launch_bounds__(256) void transpose_bf16_kernel(
    const float* __restrict__ in, u16* __restrict__ out, int R, int C, int rs, int ro) {
  __shared__ float tile[32][33];
  const int cb = blockIdx.x * 32, rb = blockIdx.y * 32;
  const int tx = threadIdx.x, ty = threadIdx.y;  // (32,8)
#pragma unroll
  for (int i = 0; i < 32; i += 8)
    tile[ty + i][tx] = in[(size_t)(rb + ty + i) * C + (cb + tx)];
  __syncthreads();
#pragma unroll
  for (int i = 0; i < 32; i += 8)
    out[((size_t)(cb + ty + i) * rs + ro) * R + (rb + tx)] = f2bf(tile[tx][ty + i]);
}

// ---------------------------------------------------------------- LayerNorm (+optional lw softmax)
template <bool WITH_LW>
__global__ __launch_bounds__(256) void ln_kernel(
    const float* __restrict__ x, const float* __restrict__ sc, const float* __restrict__ bi,
    u16* __restrict__ hout,
    const float* __restrict__ lvlw, const float* __restrict__ lvlb,
    float* __restrict__ lwout) {
  const int tid = threadIdx.x;
  const int row = blockIdx.x;
  const int wv = tid >> 6, ln = tid & 63;
  const float* xr = x + (size_t)row * 2048;
  f32x4 a0 = *(const f32x4*)(xr + tid * 4);
  f32x4 a1 = *(const f32x4*)(xr + 1024 + tid * 4);
  float s = a0[0] + a0[1] + a0[2] + a0[3] + a1[0] + a1[1] + a1[2] + a1[3];
  float q = a0[0]*a0[0] + a0[1]*a0[1] + a0[2]*a0[2] + a0[3]*a0[3]
          + a1[0]*a1[0] + a1[1]*a1[1] + a1[2]*a1[2] + a1[3]*a1[3];
#pragma unroll
  for (int off = 32; off; off >>= 1) { s += __shfl_down(s, off); q += __shfl_down(q, off); }
  __shared__ float red[8];
  __shared__ float stats[2];
  if (ln == 0) { red[wv] = s; red[4 + wv] = q; }
  __syncthreads();
  if (tid == 0) {
    float S1 = red[0] + red[1] + red[2] + red[3];
    float S2 = red[4] + red[5] + red[6] + red[7];
    float m = S1 * (1.f / 2048.f);
    float var = S2 * (1.f / 2048.f) - m * m;
    stats[0] = m;
    stats[1] = rsqrtf(var + 1e-5f);
  }
  __syncthreads();
  const float m = stats[0], rs = stats[1];
  f32x4 s0 = *(const f32x4*)(sc + tid * 4), s1 = *(const f32x4*)(sc + 1024 + tid * 4);
  f32x4 b0 = *(const f32x4*)(bi + tid * 4), b1 = *(const f32x4*)(bi + 1024 + tid * 4);
  float h0[4], h1[4];
  u16x4 o0, o1;
#pragma unroll
  for (int e = 0; e < 4; e++) {
    h0[e] = (a0[e] - m) * rs * s0[e] + b0[e];
    h1[e] = (a1[e] - m) * rs * s1[e] + b1[e];
    o0[e] = f2bf(h0[e]);
    o1[e] = f2bf(h1[e]);
  }
  u16* hr = hout + (size_t)row * 2048;
  *(u16x4*)(hr + tid * 4) = o0;
  *(u16x4*)(hr + 1024 + tid * 4) = o1;

  if constexpr (WITH_LW) {
    f32x4 acc = (f32x4){0.f, 0.f, 0.f, 0.f};
#pragma unroll
    for (int e = 0; e < 4; e++)
      acc += (*(const f32x4*)(lvlw + (size_t)(tid * 4 + e) * 4)) * h0[e];
#pragma unroll
    for (int e = 0; e < 4; e++)
      acc += (*(const f32x4*)(lvlw + (size_t)(1024 + tid * 4 + e) * 4)) * h1[e];
#pragma unroll
    for (int off = 32; off; off >>= 1) {
      acc[0] += __shfl_down(acc[0], off);
      acc[1] += __shfl_down(acc[1], off);
      acc[2] += __shfl_down(acc[2], off);
      acc[3] += __shfl_down(acc[3], off);
    }
    __shared__ float red4[16];
    if (ln == 0) {
      red4[wv * 4 + 0] = acc[0]; red4[wv * 4 + 1] = acc[1];
      red4[wv * 4 + 2] = acc[2]; red4[wv * 4 + 3] = acc[3];
    }
    __syncthreads();
    if (tid == 0) {
      float lg[4];
#pragma unroll
      for (int d = 0; d < 4; d++)
        lg[d] = red4[d] + red4[4 + d] + red4[8 + d] + red4[12 + d] + lvlb[d];
      float mx = fmaxf(fmaxf(lg[0], lg[1]), fmaxf(lg[2], lg[3]));
      float e0 = expf(lg[0] - mx), e1 = expf(lg[1] - mx), e2 = expf(lg[2] - mx), e3 = expf(lg[3] - mx);
      float inv = 1.f / (e0 + e1 + e2 + e3);
      float* lr = lwout + (size_t)row * 4;
      lr[0] = e0 * inv; lr[1] = e1 * inv; lr[2] = e2 * inv; lr[3] = e3 * inv;
    }
  }
}

// ---------------------------------------------------------------- attention mix
__global__ __launch_bounds__(256) void mix_u_kernel(
    const u16* __restrict__ v, const u16* __restrict__ k, const u16* __restrict__ r,
    const float* __restrict__ lw, const float* __restrict__ att, const float* __restrict__ td,
    u16* __restrict__ u) {
  const size_t i4 = ((size_t)blockIdx.x * 256 + threadIdx.x) * 4;
  const int row = (int)(i4 >> 11);
  const int hh = (int)(i4 & 2047);
  const int b = row >> 11;
  f32x4 lwv = *(const f32x4*)(lw + (size_t)row * 4);
  u16x4 k_ = *(const u16x4*)(k + i4);
  u16x4 v_ = *(const u16x4*)(v + i4);
  u16x4 r_ = *(const u16x4*)(r + i4);
  f32x4 kv, acc = (f32x4){0.f, 0.f, 0.f, 0.f};
#pragma unroll
  for (int e = 0; e < 4; e++) kv[e] = bf2f(k_[e]) * bf2f(v_[e]);
#pragma unroll
  for (int d = 0; d < 4; d++) {
    f32x4 as_ = *(const f32x4*)(att + (size_t)(b * 4 + d) * 2048 + hh);
    f32x4 tdv = *(const f32x4*)(td + (size_t)d * 2048 + hh);
#pragma unroll
    for (int e = 0; e < 4; e++)
      acc[e] += lwv[d] * (as_[e] * expf(-expf(tdv[e])) + kv[e]);
  }
  u16x4 o;
#pragma unroll
  for (int e = 0; e < 4; e++) o[e] = f2bf(bf2f(r_[e]) * acc[e]);
  *(u16x4*)(u + i4) = o;
}

// ---------------------------------------------------------------- token shift mix
__global__ __launch_bounds__(256) void shift_mix_kernel(
    const u16* __restrict__ h2, const float* __restrict__ cm, const float* __restrict__ tmk,
    u16* __restrict__ km) {
  const size_t i4 = ((size_t)blockIdx.x * 256 + threadIdx.x) * 4;
  const int hh = (int)(i4 & 2047);
  const int row = (int)(i4 >> 11);
  const int b = row >> 11;
  const int t = row & 2047;
  f32x4 tk = *(const f32x4*)(tmk + hh);
  u16x4 cur_ = *(const u16x4*)(h2 + i4);
  f32x4 prev;
  if (t == 0) {
    prev = *(const f32x4*)(cm + (size_t)b * 2048 + hh);
  } else {
    u16x4 p_ = *(const u16x4*)(h2 + i4 - 2048);
#pragma unroll
    for (int e = 0; e < 4; e++) prev[e] = bf2f(p_[e]);
  }
  u16x4 o;
#pragma unroll
  for (int e = 0; e < 4; e++) {
    float c = bf2f(cur_[e]);
    o[e] = f2bf(c * tk[e] + prev[e] * (1.f - tk[e]));
  }
  *(u16x4*)(km + i4) = o;
}

// ---------------------------------------------------------------- GEMM: C[M,N] = A[M,K] @ Bt[N,K]^T
enum { EPI_ADDX = 0, EPI_RELU2, EPI_VKR, EPI_VG };

template <int EPI>
__global__ __launch_bounds__(256) void gemm_bt(
    const u16* __restrict__ A, const u16* __restrict__ Bt,
    void* o0, void* o1, void* o2, const float* __restrict__ aux_f,
    int M, int N, int K) {
  __shared__ __align__(16) u16 ldsA[128 * 32];
  __shared__ __align__(16) u16 ldsB[128 * 32];
  const int tid = threadIdx.x;
  const int wave = tid >> 6, lane = tid & 63;
  const int qd = lane >> 4, l16 = lane & 15;
  const int m0 = blockIdx.y * 128, n0 = blockIdx.x * 128;
  const int wm = (wave >> 1) * 64, wn = (wave & 1) * 64;

  const u16* Ag = A + (size_t)(m0 + (tid >> 2)) * K + ((tid & 3) << 3);
  const u16* Bg = Bt + (size_t)(n0 + (tid >> 2)) * K + ((tid & 3) << 3);
  const size_t half = (size_t)64 * K;
  u16* la = ldsA + wave * 512;  // wave-uniform base; HW scatters lane*16B
  u16* lb = ldsB + wave * 512;

  f32x4 acc[4][4];
#pragma unroll
  for (int i = 0; i < 4; i++)
#pragma unroll
    for (int j = 0; j < 4; j++) acc[i][j] = (f32x4){0.f, 0.f, 0.f, 0.f};

  for (int kt = 0; kt < K; kt += 32) {
    __builtin_amdgcn_global_load_lds(GAS(Ag + kt), LAS(la), 16, 0, 0);
    __builtin_amdgcn_global_load_lds(GAS(Ag + half + kt), LAS(la + 2048), 16, 0, 0);
    __builtin_amdgcn_global_load_lds(GAS(Bg + kt), LAS(lb), 16, 0, 0);
    __builtin_amdgcn_global_load_lds(GAS(Bg + half + kt), LAS(lb + 2048), 16, 0, 0);
    __syncthreads();
    short8 af[4], bfr[4];
#pragma unroll
    for (int i = 0; i < 4; i++)
      af[i] = *(const short8*)(ldsA + (wm + i * 16 + l16) * 32 + qd * 8);
#pragma unroll
    for (int j = 0; j < 4; j++)
      bfr[j] = *(const short8*)(ldsB + (wn + j * 16 + l16) * 32 + qd * 8);
#pragma unroll
    for (int i = 0; i < 4; i++)
#pragma unroll
      for (int j = 0; j < 4; j++)
        acc[i][j] = __builtin_amdgcn_mfma_f32_16x16x32_bf16(af[i], bfr[j], acc[i][j], 0, 0, 0);
    __syncthreads();
  }

#pragma unroll
  for (int i = 0; i < 4; i++)
#pragma unroll
    for (int j = 0; j < 4; j++)
#pragma unroll
      for (int rg = 0; rg < 4; rg++) {
        const int rr = m0 + wm + i * 16 + qd * 4 + rg;   // C/D: row = quad*4+reg
        const int cc = n0 + wn + j * 16 + l16;           //      col = lane&15
        const float vv = acc[i][j][rg];
        if constexpr (EPI == EPI_ADDX) {
          const size_t idx = (size_t)rr * N + cc;
          ((float*)o0)[idx] = vv + aux_f[idx];
        } else if constexpr (EPI == EPI_RELU2) {
          const size_t idx = (size_t)rr * N + cc;
          float t = vv > 0.f ? vv : 0.f;
          ((u16*)o0)[idx] = f2bf(t * t);
        } else if constexpr (EPI == EPI_VKR) {
          // N=6144 = [v|k|r]; 128-wide blocks never straddle a 2048 boundary
          const int seg = cc >> 11, local = cc & 2047;
          const size_t idx = (size_t)rr * 2048 + local;
          if (seg == 0)      ((u16*)o0)[idx] = f2bf(vv);
          else if (seg == 1) ((u16*)o1)[idx] = f2bf(vv);
          else               ((u16*)o2)[idx] = f2bf(sigmoidf_(vv));
        } else {  // EPI_VG: Bt rows interleaved (even=Wval col, odd=Wgate col)
          const float part = __shfl_xor(vv, 1);  // partner lane: same out col, other matrix
          if ((l16 & 1) == 0) {
            const size_t idx = (size_t)rr * 2048 + (size_t)(cc >> 1);
            ((float*)o0)[idx] = aux_f[idx] + vv * sigmoidf_(part);
          }
        }
      }
}

// ---------------------------------------------------------------- launch
extern "C" void kernel_launch(void* const* d_in, const int* in_sizes, int n_in,
                              void* d_out, int out_size, void* d_ws, size_t ws_size,
                              hipStream_t stream) {
  const float* x = (const float*)d_in[0];
  const float* att_state = (const float*)d_in[1];
  const float* cm_state = (const float*)d_in[2];
  const float* ln1_s = (const float*)d_in[3];
  const float* ln1_b = (const float*)d_in[4];
  const float* ln2_s = (const float*)d_in[5];
  const float* ln2_b = (const float*)d_in[6];
  const float* td = (const float*)d_in[7];
  const float* lvl_w = (const float*)d_in[8];
  const float* lvl_b = (const float*)d_in[9];
  const float* Wv = (const float*)d_in[10];
  const float* Wk = (const float*)d_in[11];
  const float* Wr = (const float*)d_in[12];
  const float* Wo = (const float*)d_in[13];
  const float* tmk = (const float*)d_in[14];
  const float* Wkey = (const float*)d_in[15];
  const float* Wval = (const float*)d_in[16];
  const float* Wgate = (const float*)d_in[17];
  float* out = (float*)d_out;

  const size_t S = 8192ull * 2048ull;     // B*T*H
  const size_t S4 = 8192ull * 8192ull;    // B*T*FF
  char* ws = (char*)d_ws;
  u16* bufW = (u16*)(ws);                 // slot0 32MB: Bt for vkr(24MB)/Wo(8MB)/Wkey(32MB)
  u16* hbuf = (u16*)(ws + 1 * S * 2);     // slot1: h, then u
  u16* vbuf = (u16*)(ws + 2 * S * 2);     // slot2: v, then h2
  u16* kbuf = (u16*)(ws + 3 * S * 2);     // slot3: k, then km
  u16* rbuf = (u16*)(ws + 4 * S * 2);     // slot4: r
  u16* bufVG = hbuf;                      // slot1+2 (64MB): interleaved [Wval|Wgate]^T, after u/h2 die
  u16* kkbuf = (u16*)(ws + 5 * S * 2);    // 128MB: kk
  float* lwbuf = (float*)(ws + 5 * S * 2 + S4 * 2);  // 128KB: lw
  (void)in_sizes; (void)n_in; (void)out_size; (void)ws_size;

  const dim3 tb256(256);
  const dim3 ttb(32, 8);
  const dim3 gT2k(64, 64);                 // 2048x2048 transpose
  const dim3 gTkey(256, 64);               // Wkey [2048,8192]
  const dim3 gTvg(64, 256);                // Wval/Wgate [8192,2048]
  const dim3 gemm_vkr(6144 / 128, 64);     // 48x64 = 3072 blocks
  const dim3 gemm_wo(2048 / 128, 64);      // 16x64 = 1024 blocks
  const dim3 gemm_kk(8192 / 128, 64);      // 64x64 = 4096 blocks
  const dim3 gemm_vg(4096 / 128, 64);      // 32x64 = 2048 blocks
  const int elemBlocks = (int)(S / 1024);

  // ln1 -> h (bf16) + lw softmax
  ln_kernel<true><<<8192, tb256, 0, stream>>>(x, ln1_s, ln1_b, hbuf, lvl_w, lvl_b, lwbuf);
  // Bt = [Wv^T ; Wk^T ; Wr^T] rows 0..6143
  transpose_bf16_kernel<<<gT2k, ttb, 0, stream>>>(Wv, bufW, 2048, 2048, 1, 0);
  transpose_bf16_kernel<<<gT2k, ttb, 0, stream>>>(Wk, bufW, 2048, 2048, 1, 2048);
  transpose_bf16_kernel<<<gT2k, ttb, 0, stream>>>(Wr, bufW, 2048, 2048, 1, 4096);
  // [v|k|r] fused GEMM
  gemm_bt<EPI_VKR><<<gemm_vkr, tb256, 0, stream>>>(hbuf, bufW, vbuf, kbuf, rbuf, nullptr, 8192, 6144, 2048);
  // u -> hbuf (h dead)
  mix_u_kernel<<<elemBlocks, tb256, 0, stream>>>(vbuf, kbuf, rbuf, lwbuf, att_state, td, hbuf);
  // x1 = x + u@Wo -> d_out (fp32)
  transpose_bf16_kernel<<<gT2k, ttb, 0, stream>>>(Wo, bufW, 2048, 2048, 1, 0);
  gemm_bt<EPI_ADDX><<<gemm_wo, tb256, 0, stream>>>(hbuf, bufW, out, nullptr, nullptr, x, 8192, 2048, 2048);
  // h2 = ln2(x1) -> vbuf (v dead)
  ln_kernel<false><<<8192, tb256, 0, stream>>>(out, ln2_s, ln2_b, vbuf, nullptr, nullptr, nullptr);
  // km -> kbuf (k dead)
  shift_mix_kernel<<<elemBlocks, tb256, 0, stream>>>(vbuf, cm_state, tmk, kbuf);
  // kk = relu(km@Wkey)^2 -> kkbuf
  transpose_bf16_kernel<<<gTkey, ttb, 0, stream>>>(Wkey, bufW, 2048, 8192, 1, 0);
  gemm_bt<EPI_RELU2><<<gemm_kk, tb256, 0, stream>>>(kbuf, bufW, kkbuf, nullptr, nullptr, nullptr, 8192, 8192, 2048);
  // interleaved [Wval|Wgate]^T into slot1+2 (u, h2 dead now)
  transpose_bf16_kernel<<<gTvg, ttb, 0, stream>>>(Wval, bufVG, 8192, 2048, 2, 0);
  transpose_bf16_kernel<<<gTvg, ttb, 0, stream>>>(Wgate, bufVG, 8192, 2048, 2, 1);
  // out = x1 + (kk@Wval)*sigmoid(kk@Wgate), fused, in-place on d_out
  gemm_bt<EPI_VG><<<gemm_vg, tb256, 0, stream>>>(kkbuf, bufVG, out, nullptr, nullptr, out, 8192, 4096, 8192);
}